// Round 5
// baseline (882.049 us; speedup 1.0000x reference)
//
#include <hip/hip_runtime.h>
#include <math.h>

// Problem constants (B=1)
#define MM 1024
#define DD 512
#define CC 128
#define LDSR 528   // A row stride in ushorts: 1056 B = 16B-aligned, banks spread evenly (8/bank)

// ws layout (floats):
//  H[1024][3072]      @ 0        (0..1023 ms-hidden, 1024.. src_proj, 2048.. ant_proj)
//  slow[1024][128]    @ 3145728
//  spk_proj[2][1024]  @ 3276800
//  bkt_proj[10][1024] @ 3278848
//  ms[1024]           @ 3289088
//  lossp[1024]        @ 3290112
//  embb bf16[1024][512]  @ 3291136
//  Wall bf16[4096][512]  @ 3553280
//    rows: [0,1024)=ms_W0^T, [1024,2048)=W_src^T, [2048,3072)=W_ant^T, [3072,4096)=W_prod^T

typedef __attribute__((ext_vector_type(8))) short bf16x8;
typedef __attribute__((ext_vector_type(4))) float f32x4;
typedef __attribute__((ext_vector_type(16))) float f32x16;

__device__ __forceinline__ ushort bf16_rn(float x) {
    uint u = __float_as_uint(x);
    uint r = u + 0x7fffu + ((u >> 16) & 1u);
    return (ushort)(r >> 16);
}
__device__ __forceinline__ float bf16_to_f(ushort u) {
    return __uint_as_float(((uint)u) << 16);
}

// ---------------- prep: emb fp32 -> bf16
__global__ __launch_bounds__(256) void prep_emb(const float* __restrict__ emb,
                                                ushort* __restrict__ embb)
{
    int i = blockIdx.x * 256 + threadIdx.x;
    float2 v = ((const float2*)emb)[i];
    ushort2 o;
    o.x = bf16_rn(v.x);
    o.y = bf16_rn(v.y);
    ((ushort2*)embb)[i] = o;
}

// ---------------- prep: transpose+convert all W0 blocks -> Wall[4096 n][512 k] bf16
__global__ __launch_bounds__(256) void prep_wall(const float* __restrict__ ms_W0,
                                                 const float* __restrict__ sp_W0,
                                                 ushort* __restrict__ Wall)
{
    __shared__ float t[64][65];
    const int k0 = blockIdx.x * 64;   // 8
    const int n0 = blockIdx.y * 64;   // 64
    const int g = n0 >> 10;
    const float* src = (g == 0) ? ms_W0 : (sp_W0 + (size_t)(g - 1) * 512 * 1024);
    const int col0 = n0 & 1023;
    const int tr = threadIdx.x >> 6, tc = threadIdx.x & 63;
#pragma unroll
    for (int i = 0; i < 16; ++i) {
        int k = tr + i * 4;
        t[k][tc] = src[(size_t)(k0 + k) * 1024 + col0 + tc];
    }
    __syncthreads();
    const int f = threadIdx.x >> 2;
    const int c4 = threadIdx.x & 3;
    ushort tmp[16];
#pragma unroll
    for (int j = 0; j < 16; ++j) tmp[j] = bf16_rn(t[c4 * 16 + j][f]);
    uint4* dst = (uint4*)(Wall + (size_t)(n0 + f) * 512 + k0 + c4 * 16);
    dst[0] = *(uint4*)&tmp[0];
    dst[1] = *(uint4*)&tmp[8];
}

// ---------------- H = emb @ [ms_W0 | W_src | W_ant] via MFMA (1024x512x3072)
__global__ __launch_bounds__(256) void gemm_h_mfma(
    const ushort* __restrict__ embb, const ushort* __restrict__ Wall,
    float* __restrict__ H)
{
    const int n0 = blockIdx.x * 128;  // 24
    const int m0 = blockIdx.y * 128;  // 8
    const int lane = threadIdx.x & 63, wave = threadIdx.x >> 6;
    const int wx = wave & 1, wy = wave >> 1;
    const int l15 = lane & 15, lq = lane >> 4;

    const ushort* arow[4];
#pragma unroll
    for (int mi = 0; mi < 4; ++mi)
        arow[mi] = embb + (size_t)(m0 + wy * 64 + mi * 16 + l15) * 512;
    const ushort* brow[4];
#pragma unroll
    for (int ni = 0; ni < 4; ++ni)
        brow[ni] = Wall + (size_t)(n0 + wx * 64 + ni * 16 + l15) * 512;

    f32x4 acc[4][4];
#pragma unroll
    for (int i = 0; i < 4; ++i)
#pragma unroll
        for (int j = 0; j < 4; ++j) acc[i][j] = (f32x4)0.f;

    for (int kt = 0; kt < 512; kt += 32) {
        const int ko = kt + lq * 8;
        bf16x8 av[4], bv[4];
#pragma unroll
        for (int mi = 0; mi < 4; ++mi) av[mi] = *(const bf16x8*)(arow[mi] + ko);
#pragma unroll
        for (int ni = 0; ni < 4; ++ni) bv[ni] = *(const bf16x8*)(brow[ni] + ko);
#pragma unroll
        for (int mi = 0; mi < 4; ++mi)
#pragma unroll
            for (int ni = 0; ni < 4; ++ni)
                acc[mi][ni] = __builtin_amdgcn_mfma_f32_16x16x32_bf16(av[mi], bv[ni], acc[mi][ni], 0, 0, 0);
    }
#pragma unroll
    for (int mi = 0; mi < 4; ++mi)
#pragma unroll
        for (int r = 0; r < 4; ++r) {
            int mrow = m0 + wy * 64 + mi * 16 + lq * 4 + r;
#pragma unroll
            for (int ni = 0; ni < 4; ++ni)
                H[(size_t)mrow * 3072 + n0 + wx * 64 + ni * 16 + l15] = acc[mi][ni][r];
        }
}

// ---------------- small projections
__global__ void small_proj(const float* __restrict__ speaker_emb,
                           const float* __restrict__ bucket_emb,
                           const float* __restrict__ sp_W0,
                           float* __restrict__ spk_proj, float* __restrict__ bkt_proj)
{
    int r = blockIdx.x; // 0..11
    const float* e; const float* W; float* out;
    if (r < 2) { e = speaker_emb + r * 20; W = sp_W0 + (size_t)1536 * 1024; out = spk_proj + r * 1024; }
    else       { e = bucket_emb + (r - 2) * 20; W = sp_W0 + (size_t)1556 * 1024; out = bkt_proj + (r - 2) * 1024; }
    float ek[20];
#pragma unroll
    for (int k = 0; k < 20; ++k) ek[k] = e[k];
    for (int f = threadIdx.x; f < 1024; f += blockDim.x) {
        float s = 0.f;
#pragma unroll
        for (int k = 0; k < 20; ++k) s = fmaf(ek[k], W[(size_t)k * 1024 + f], s);
        out[f] = s;
    }
}

// ---------------- mention scores
__global__ __launch_bounds__(256) void mention_score(
    const float* __restrict__ H, const float* __restrict__ ms_b0,
    const float* __restrict__ ms_W1, const float* __restrict__ ms_b1,
    float* __restrict__ ms)
{
    int m = blockIdx.x;
    float v = 0.f;
    for (int f = threadIdx.x; f < 1024; f += 256) {
        float h = H[(size_t)m * 3072 + f] + ms_b0[f];
        v += fmaxf(h, 0.f) * ms_W1[f];
    }
#pragma unroll
    for (int o = 1; o < 64; o <<= 1) v += __shfl_xor(v, o);
    __shared__ float sm[4];
    if ((threadIdx.x & 63) == 0) sm[threadIdx.x >> 6] = v;
    __syncthreads();
    if (threadIdx.x == 0) ms[m] = sm[0] + sm[1] + sm[2] + sm[3] + ms_b1[0];
}

// ---------------- pair scorer: 1024 thr = 16 waves (4/SIMD); 32x32x16 MFMA; A in LDS
__global__ __launch_bounds__(1024) void pair_mfma(
    const ushort* __restrict__ embb, const ushort* __restrict__ Wt,
    const float* __restrict__ H, const float* __restrict__ spk_proj,
    const float* __restrict__ bkt_proj, const float* __restrict__ sp_b0,
    const float* __restrict__ sp_W1, const int* __restrict__ speaker,
    float* __restrict__ slow)
{
    extern __shared__ ushort Alds[];                  // 128*LDSR ushorts
    float* red = (float*)(Alds + 128 * LDSR);         // 16*128 floats
    int* meta_ss = (int*)(red + 16 * 128);            // 128 ints
    int* meta_bk = meta_ss + 128;                     // 128 ints
    const int m = blockIdx.x;
    const int tid = threadIdx.x;
    const int spk_m = speaker[m];

    // ---- build A[c][k] = bf16(em[k]*ea[k]) in LDS + per-c metadata
    {
        const int c = tid >> 3;                       // 0..127
        const int kh = (tid & 7) * 64;
        int a = m - 1 - c; if (a < 0) a = 0;
        const ushort* ea = embb + (size_t)a * 512 + kh;
        const ushort* em = embb + (size_t)m * 512 + kh;
        ushort* dst = Alds + c * LDSR + kh;
#pragma unroll
        for (int j = 0; j < 64; j += 8) {
            bf16x8 va = *(const bf16x8*)(ea + j);
            bf16x8 vm = *(const bf16x8*)(em + j);
            uint pr[4];
#pragma unroll
            for (int p = 0; p < 4; ++p) {
                float q0 = bf16_to_f((ushort)va[2 * p])     * bf16_to_f((ushort)vm[2 * p]);
                float q1 = bf16_to_f((ushort)va[2 * p + 1]) * bf16_to_f((ushort)vm[2 * p + 1]);
                pr[p] = __builtin_amdgcn_perm(__float_as_uint(q1), __float_as_uint(q0), 0x07060302u);
            }
            *(bf16x8*)(dst + j) = *(bf16x8*)pr;
        }
        if ((tid & 7) == 0) {
            meta_ss[c] = (speaker[a] == spk_m) ? 1 : 0;
            int off = c + 1;
            int bk;
            if (off <= 4) bk = off;
            else { bk = 31 - __clz(off) + 3; if (bk > 9) bk = 9; }
            meta_bk[c] = bk;
        }
    }
    __syncthreads();

    const int lane = tid & 63;
    const int wave = __builtin_amdgcn_readfirstlane(tid >> 6);   // 0..15, wave-uniform
    const int l31 = lane & 31, k5 = lane >> 5;
    const int f0 = wave * 64;

    // B: lane reads Wt[f0 + ni*32 + l31][kt + k5*8 .. +8]
    const ushort* bb0 = Wt + (size_t)f0 * 512 + l31 * 512 + k5 * 8;
    const ushort* bb1 = bb0 + 32 * 512;
    const ushort* abase = Alds + l31 * LDSR + k5 * 8;

    // per-f-chunk epilogue constants (hoisted: f0 fixed per wave)
    float srcb[2], w1v[2], sp0v[2], sp1v[2], bk9v[2];
#pragma unroll
    for (int ni = 0; ni < 2; ++ni) {
        int fcol = f0 + ni * 32 + l31;
        srcb[ni] = H[(size_t)m * 3072 + 1024 + fcol] + sp_b0[fcol];
        w1v[ni]  = sp_W1[fcol];
        sp0v[ni] = spk_proj[fcol];
        sp1v[ni] = spk_proj[1024 + fcol];
        bk9v[ni] = bkt_proj[9 * 1024 + fcol];
    }

    for (int pass = 0; pass < 2; ++pass) {
        const int c0 = pass * 64;
        const ushort* ap = abase + c0 * LDSR;
        f32x16 acc[2][2];
#pragma unroll
        for (int i = 0; i < 2; ++i)
#pragma unroll
            for (int j = 0; j < 2; ++j) acc[i][j] = (f32x16)0.f;

        // ping-pong 2-deep pipeline, k-step = 16
        bf16x8 aA[2], bA[2], aB[2], bB[2];
        aA[0] = *(const bf16x8*)(ap);
        aA[1] = *(const bf16x8*)(ap + 32 * LDSR);
        bA[0] = *(const bf16x8*)(bb0);
        bA[1] = *(const bf16x8*)(bb1);
        for (int kt = 0; kt < 512; kt += 32) {
            const int k1 = kt + 16;
            aB[0] = *(const bf16x8*)(ap + k1);
            aB[1] = *(const bf16x8*)(ap + 32 * LDSR + k1);
            bB[0] = *(const bf16x8*)(bb0 + k1);
            bB[1] = *(const bf16x8*)(bb1 + k1);
#pragma unroll
            for (int mi = 0; mi < 2; ++mi)
#pragma unroll
                for (int ni = 0; ni < 2; ++ni)
                    acc[mi][ni] = __builtin_amdgcn_mfma_f32_32x32x16_bf16(aA[mi], bA[ni], acc[mi][ni], 0, 0, 0);
            const int k2 = (kt + 32) & 511;   // last-iter wrap: valid, unused
            aA[0] = *(const bf16x8*)(ap + k2);
            aA[1] = *(const bf16x8*)(ap + 32 * LDSR + k2);
            bA[0] = *(const bf16x8*)(bb0 + k2);
            bA[1] = *(const bf16x8*)(bb1 + k2);
#pragma unroll
            for (int mi = 0; mi < 2; ++mi)
#pragma unroll
                for (int ni = 0; ni < 2; ++ni)
                    acc[mi][ni] = __builtin_amdgcn_mfma_f32_32x32x16_bf16(aB[mi], bB[ni], acc[mi][ni], 0, 0, 0);
        }

        // ---- epilogue: C/D 32x32 layout: col=lane&31, row=(reg&3)+8*(reg>>2)+4*(lane>>5)
#pragma unroll
        for (int mi = 0; mi < 2; ++mi) {
#pragma unroll
            for (int reg = 0; reg < 16; ++reg) {
                const int c = c0 + mi * 32 + 4 * k5 + (reg & 3) + 8 * (reg >> 2);
                int a = m - 1 - c; if (a < 0) a = 0;
                const int ss = meta_ss[c];
                const float* antp = H + (size_t)a * 3072 + 2048;
                float s = 0.f;
#pragma unroll
                for (int ni = 0; ni < 2; ++ni) {
                    const int fcol = f0 + ni * 32 + l31;
                    float bval = pass ? bk9v[ni] : bkt_proj[(size_t)meta_bk[c] * 1024 + fcol];
                    float pre = acc[mi][ni][reg] + srcb[ni] + antp[fcol] + (ss ? sp1v[ni] : sp0v[ni]) + bval;
                    s += fmaxf(pre, 0.f) * w1v[ni];
                }
                s += __shfl_xor(s, 1); s += __shfl_xor(s, 2); s += __shfl_xor(s, 4);
                s += __shfl_xor(s, 8); s += __shfl_xor(s, 16);
                if (l31 == 0) red[wave * 128 + c] = s;
            }
        }
    }
    __syncthreads();
    if (tid < 128) {
        float s = 0.f;
#pragma unroll
        for (int i = 0; i < 16; ++i) s += red[i * 128 + tid];
        slow[(size_t)m * 128 + tid] = s;
    }
}

// ---------------- softmax + per-mention loss
__device__ __forceinline__ float bsum2(float v, float* sm) {
#pragma unroll
    for (int o = 1; o < 64; o <<= 1) v += __shfl_xor(v, o);
    __syncthreads();
    if ((threadIdx.x & 63) == 0) sm[threadIdx.x >> 6] = v;
    __syncthreads();
    return sm[0] + sm[1];
}
__device__ __forceinline__ float bmax2(float v, float* sm) {
#pragma unroll
    for (int o = 1; o < 64; o <<= 1) v = fmaxf(v, __shfl_xor(v, o));
    __syncthreads();
    if ((threadIdx.x & 63) == 0) sm[threadIdx.x >> 6] = v;
    __syncthreads();
    return fmaxf(sm[0], sm[1]);
}

__global__ __launch_bounds__(128) void softmax_loss(
    const float* __restrict__ slow, const float* __restrict__ ms,
    const float* __restrict__ sp_b1, const int* __restrict__ cluster,
    float* __restrict__ out, float* __restrict__ loss_partial)
{
    const int m = blockIdx.x, c = threadIdx.x;
    __shared__ float sm[2];
    const int raw = m - 1 - c;
    const bool maskv = raw >= 0;
    const int a = maskv ? raw : 0;
    float score = slow[(size_t)m * 128 + c] + sp_b1[0] + ms[m] + ms[a];
    if (!maskv) score = -INFINITY;

    float mx = fmaxf(bmax2(score, sm), 0.f);
    float e = expf(score - mx);
    float e0 = expf(0.f - mx);
    float sum = bsum2(e, sm) + e0;
    float p = e / sum, p0 = e0 / sum;
    const float eps = 1e-6f;
    p  = fminf(fmaxf(p,  eps), 1.f - eps);
    p0 = fminf(fmaxf(p0, eps), 1.f - eps);
    float sum2 = bsum2(p, sm) + p0;
    p /= sum2; p0 /= sum2;
    out[(size_t)m * 129 + 1 + c] = p;
    if (c == 0) out[(size_t)m * 129] = p0;

    const int cid = cluster[m];
    const bool lbl = maskv && (cid > 0) && (cluster[a] == cid);
    float anyc = bsum2(lbl ? 1.f : 0.f, sm);
    float lsum = bsum2(lbl ? -logf(p) : 0.f, sm);
    if (c == 0) {
        if (anyc == 0.f) lsum += -logf(p0);
        loss_partial[m] = lsum;
    }
}

__global__ void loss_sum(const float* __restrict__ lp, float* __restrict__ out) {
    float v = 0.f;
    for (int i = threadIdx.x; i < 1024; i += 256) v += lp[i];
#pragma unroll
    for (int o = 1; o < 64; o <<= 1) v += __shfl_xor(v, o);
    __shared__ float sm[4];
    if ((threadIdx.x & 63) == 0) sm[threadIdx.x >> 6] = v;
    __syncthreads();
    if (threadIdx.x == 0) out[(size_t)1024 * 129] = sm[0] + sm[1] + sm[2] + sm[3];
}

extern "C" void kernel_launch(void* const* d_in, const int* in_sizes, int n_in,
                              void* d_out, int out_size, void* d_ws, size_t ws_size,
                              hipStream_t stream)
{
    const float* emb   = (const float*)d_in[0];
    const int*   clus  = (const int*)  d_in[1];
    const int*   spk   = (const int*)  d_in[2];
    const float* ms_W0 = (const float*)d_in[3];
    const float* ms_b0 = (const float*)d_in[4];
    const float* ms_W1 = (const float*)d_in[5];
    const float* ms_b1 = (const float*)d_in[6];
    const float* sp_W0 = (const float*)d_in[7];
    const float* sp_b0 = (const float*)d_in[8];
    const float* sp_W1 = (const float*)d_in[9];
    const float* sp_b1 = (const float*)d_in[10];
    const float* spke  = (const float*)d_in[11];
    const float* bkte  = (const float*)d_in[12];

    float* ws = (float*)d_ws;
    float* H        = ws;
    float* slow     = ws + 3145728;
    float* spk_proj = ws + 3276800;
    float* bkt_proj = ws + 3278848;
    float* msc      = ws + 3289088;
    float* lossp    = ws + 3290112;
    ushort* embb    = (ushort*)(ws + 3291136);
    ushort* Wall    = (ushort*)(ws + 3553280);
    ushort* Wt      = Wall + (size_t)3072 * 512;
    float* out = (float*)d_out;

    const int pair_lds = 128 * LDSR * 2 + 16 * 128 * 4 + 256 * 4;

    static bool attr_set = false;
    if (!attr_set) {
        hipFuncSetAttribute((const void*)pair_mfma,
                            hipFuncAttributeMaxDynamicSharedMemorySize,
                            pair_lds);
        attr_set = true;
    }

    hipLaunchKernelGGL(prep_emb, dim3(1024), dim3(256), 0, stream, emb, embb);
    hipLaunchKernelGGL(prep_wall, dim3(8, 64), dim3(256), 0, stream, ms_W0, sp_W0, Wall);
    hipLaunchKernelGGL(gemm_h_mfma, dim3(24, 8), dim3(256), 0, stream, embb, Wall, H);
    hipLaunchKernelGGL(small_proj, dim3(12), dim3(256), 0, stream, spke, bkte, sp_W0, spk_proj, bkt_proj);
    hipLaunchKernelGGL(mention_score, dim3(1024), dim3(256), 0, stream, H, ms_b0, ms_W1, ms_b1, msc);
    hipLaunchKernelGGL(pair_mfma, dim3(1024), dim3(1024), pair_lds, stream,
                       embb, Wt, H, spk_proj, bkt_proj, sp_b0, sp_W1, spk, slow);
    hipLaunchKernelGGL(softmax_loss, dim3(1024), dim3(128), 0, stream,
                       slow, msc, sp_b1, clus, out, lossp);
    hipLaunchKernelGGL(loss_sum, dim3(1), dim3(256), 0, stream, lossp, out);
}

// Round 6
// 485.676 us; speedup vs baseline: 1.8161x; 1.8161x over previous
//
#include <hip/hip_runtime.h>
#include <math.h>

// Problem constants (B=1)
#define MM 1024
#define DD 512
#define CC 128
#define LDSR 528   // A row stride in ushorts: 1056 B = 16B-aligned, banks spread evenly

// ws layout (floats):
//  H[1024][3072]      @ 0        (0..1023 ms-hidden, 1024.. src_proj, 2048.. ant_proj)
//  slow[1024][128]    @ 3145728
//  spk_proj[2][1024]  @ 3276800
//  bkt_proj[10][1024] @ 3278848
//  ms[1024]           @ 3289088
//  lossp[1024]        @ 3290112
//  embb bf16[1024][512]  @ 3291136
//  Wall bf16[4096][512]  @ 3553280
//    rows: [0,1024)=ms_W0^T, [1024,2048)=W_src^T, [2048,3072)=W_ant^T, [3072,4096)=W_prod^T

typedef __attribute__((ext_vector_type(8))) short bf16x8;
typedef __attribute__((ext_vector_type(4))) float f32x4;
typedef __attribute__((ext_vector_type(16))) float f32x16;

__device__ __forceinline__ ushort bf16_rn(float x) {
    uint u = __float_as_uint(x);
    uint r = u + 0x7fffu + ((u >> 16) & 1u);
    return (ushort)(r >> 16);
}
__device__ __forceinline__ float bf16_to_f(ushort u) {
    return __uint_as_float(((uint)u) << 16);
}

// ---------------- prep: emb fp32 -> bf16
__global__ __launch_bounds__(256) void prep_emb(const float* __restrict__ emb,
                                                ushort* __restrict__ embb)
{
    int i = blockIdx.x * 256 + threadIdx.x;
    float2 v = ((const float2*)emb)[i];
    ushort2 o;
    o.x = bf16_rn(v.x);
    o.y = bf16_rn(v.y);
    ((ushort2*)embb)[i] = o;
}

// ---------------- prep: transpose+convert all W0 blocks -> Wall[4096 n][512 k] bf16
__global__ __launch_bounds__(256) void prep_wall(const float* __restrict__ ms_W0,
                                                 const float* __restrict__ sp_W0,
                                                 ushort* __restrict__ Wall)
{
    __shared__ float t[64][65];
    const int k0 = blockIdx.x * 64;   // 8
    const int n0 = blockIdx.y * 64;   // 64
    const int g = n0 >> 10;
    const float* src = (g == 0) ? ms_W0 : (sp_W0 + (size_t)(g - 1) * 512 * 1024);
    const int col0 = n0 & 1023;
    const int tr = threadIdx.x >> 6, tc = threadIdx.x & 63;
#pragma unroll
    for (int i = 0; i < 16; ++i) {
        int k = tr + i * 4;
        t[k][tc] = src[(size_t)(k0 + k) * 1024 + col0 + tc];
    }
    __syncthreads();
    const int f = threadIdx.x >> 2;
    const int c4 = threadIdx.x & 3;
    ushort tmp[16];
#pragma unroll
    for (int j = 0; j < 16; ++j) tmp[j] = bf16_rn(t[c4 * 16 + j][f]);
    uint4* dst = (uint4*)(Wall + (size_t)(n0 + f) * 512 + k0 + c4 * 16);
    dst[0] = *(uint4*)&tmp[0];
    dst[1] = *(uint4*)&tmp[8];
}

// ---------------- H = emb @ [ms_W0 | W_src | W_ant] via MFMA (1024x512x3072)
__global__ __launch_bounds__(256) void gemm_h_mfma(
    const ushort* __restrict__ embb, const ushort* __restrict__ Wall,
    float* __restrict__ H)
{
    const int n0 = blockIdx.x * 128;  // 24
    const int m0 = blockIdx.y * 128;  // 8
    const int lane = threadIdx.x & 63, wave = threadIdx.x >> 6;
    const int wx = wave & 1, wy = wave >> 1;
    const int l15 = lane & 15, lq = lane >> 4;

    const ushort* arow[4];
#pragma unroll
    for (int mi = 0; mi < 4; ++mi)
        arow[mi] = embb + (size_t)(m0 + wy * 64 + mi * 16 + l15) * 512;
    const ushort* brow[4];
#pragma unroll
    for (int ni = 0; ni < 4; ++ni)
        brow[ni] = Wall + (size_t)(n0 + wx * 64 + ni * 16 + l15) * 512;

    f32x4 acc[4][4];
#pragma unroll
    for (int i = 0; i < 4; ++i)
#pragma unroll
        for (int j = 0; j < 4; ++j) acc[i][j] = (f32x4)0.f;

    for (int kt = 0; kt < 512; kt += 32) {
        const int ko = kt + lq * 8;
        bf16x8 av[4], bv[4];
#pragma unroll
        for (int mi = 0; mi < 4; ++mi) av[mi] = *(const bf16x8*)(arow[mi] + ko);
#pragma unroll
        for (int ni = 0; ni < 4; ++ni) bv[ni] = *(const bf16x8*)(brow[ni] + ko);
#pragma unroll
        for (int mi = 0; mi < 4; ++mi)
#pragma unroll
            for (int ni = 0; ni < 4; ++ni)
                acc[mi][ni] = __builtin_amdgcn_mfma_f32_16x16x32_bf16(av[mi], bv[ni], acc[mi][ni], 0, 0, 0);
    }
#pragma unroll
    for (int mi = 0; mi < 4; ++mi)
#pragma unroll
        for (int r = 0; r < 4; ++r) {
            int mrow = m0 + wy * 64 + mi * 16 + lq * 4 + r;
#pragma unroll
            for (int ni = 0; ni < 4; ++ni)
                H[(size_t)mrow * 3072 + n0 + wx * 64 + ni * 16 + l15] = acc[mi][ni][r];
        }
}

// ---------------- small projections
__global__ void small_proj(const float* __restrict__ speaker_emb,
                           const float* __restrict__ bucket_emb,
                           const float* __restrict__ sp_W0,
                           float* __restrict__ spk_proj, float* __restrict__ bkt_proj)
{
    int r = blockIdx.x; // 0..11
    const float* e; const float* W; float* out;
    if (r < 2) { e = speaker_emb + r * 20; W = sp_W0 + (size_t)1536 * 1024; out = spk_proj + r * 1024; }
    else       { e = bucket_emb + (r - 2) * 20; W = sp_W0 + (size_t)1556 * 1024; out = bkt_proj + (r - 2) * 1024; }
    float ek[20];
#pragma unroll
    for (int k = 0; k < 20; ++k) ek[k] = e[k];
    for (int f = threadIdx.x; f < 1024; f += blockDim.x) {
        float s = 0.f;
#pragma unroll
        for (int k = 0; k < 20; ++k) s = fmaf(ek[k], W[(size_t)k * 1024 + f], s);
        out[f] = s;
    }
}

// ---------------- mention scores
__global__ __launch_bounds__(256) void mention_score(
    const float* __restrict__ H, const float* __restrict__ ms_b0,
    const float* __restrict__ ms_W1, const float* __restrict__ ms_b1,
    float* __restrict__ ms)
{
    int m = blockIdx.x;
    float v = 0.f;
    for (int f = threadIdx.x; f < 1024; f += 256) {
        float h = H[(size_t)m * 3072 + f] + ms_b0[f];
        v += fmaxf(h, 0.f) * ms_W1[f];
    }
#pragma unroll
    for (int o = 1; o < 64; o <<= 1) v += __shfl_xor(v, o);
    __shared__ float sm[4];
    if ((threadIdx.x & 63) == 0) sm[threadIdx.x >> 6] = v;
    __syncthreads();
    if (threadIdx.x == 0) ms[m] = sm[0] + sm[1] + sm[2] + sm[3] + ms_b1[0];
}

// ---------------- pair scorer: 1024 thr = 16 waves (4/SIMD); 32x32x16 MFMA; A in LDS
// launch_bounds (1024, 4): 4 waves/EU -> 128 combined VGPR cap. R5's missing 2nd arg
// made the compiler target 8 waves/EU (64 regs) and spill the acc tile to scratch
// (~1 GB/dispatch HBM r+w). Keep k-loop register-lean: single-buffered operands,
// epilogue constants loaded after the k-loop.
__global__ __launch_bounds__(1024, 4) void pair_mfma(
    const ushort* __restrict__ embb, const ushort* __restrict__ Wt,
    const float* __restrict__ H, const float* __restrict__ spk_proj,
    const float* __restrict__ bkt_proj, const float* __restrict__ sp_b0,
    const float* __restrict__ sp_W1, const int* __restrict__ speaker,
    float* __restrict__ slow)
{
    extern __shared__ ushort Alds[];                  // 128*LDSR ushorts
    float* red = (float*)(Alds + 128 * LDSR);         // 16*128 floats
    int* meta_ss = (int*)(red + 16 * 128);            // 128 ints
    int* meta_bk = meta_ss + 128;                     // 128 ints
    const int m = blockIdx.x;
    const int tid = threadIdx.x;
    const int spk_m = speaker[m];

    // ---- build A[c][k] = bf16(em[k]*ea[k]) in LDS + per-c metadata
    {
        const int c = tid >> 3;                       // 0..127
        const int kh = (tid & 7) * 64;
        int a = m - 1 - c; if (a < 0) a = 0;
        const ushort* ea = embb + (size_t)a * 512 + kh;
        const ushort* em = embb + (size_t)m * 512 + kh;
        ushort* dst = Alds + c * LDSR + kh;
#pragma unroll
        for (int j = 0; j < 64; j += 8) {
            bf16x8 va = *(const bf16x8*)(ea + j);
            bf16x8 vm = *(const bf16x8*)(em + j);
            uint pr[4];
#pragma unroll
            for (int p = 0; p < 4; ++p) {
                float q0 = bf16_to_f((ushort)va[2 * p])     * bf16_to_f((ushort)vm[2 * p]);
                float q1 = bf16_to_f((ushort)va[2 * p + 1]) * bf16_to_f((ushort)vm[2 * p + 1]);
                pr[p] = __builtin_amdgcn_perm(__float_as_uint(q1), __float_as_uint(q0), 0x07060302u);
            }
            *(bf16x8*)(dst + j) = *(bf16x8*)pr;
        }
        if ((tid & 7) == 0) {
            meta_ss[c] = (speaker[a] == spk_m) ? 1 : 0;
            int off = c + 1;
            int bk;
            if (off <= 4) bk = off;
            else { bk = 31 - __clz(off) + 3; if (bk > 9) bk = 9; }
            meta_bk[c] = bk;
        }
    }
    __syncthreads();

    const int lane = tid & 63;
    const int wave = __builtin_amdgcn_readfirstlane(tid >> 6);   // 0..15, wave-uniform
    const int l31 = lane & 31, k5 = lane >> 5;
    const int f0 = wave * 64;

    // B: lane reads Wt[f0 + ni*32 + l31][kt + k5*8 .. +8]
    const ushort* bb0 = Wt + (size_t)(f0 + l31) * 512 + k5 * 8;
    const ushort* bb1 = bb0 + 32 * 512;
    const ushort* abase = Alds + l31 * LDSR + k5 * 8;

    for (int pass = 0; pass < 2; ++pass) {
        const int c0 = pass * 64;
        const ushort* ap = abase + c0 * LDSR;
        f32x16 acc[2][2];
#pragma unroll
        for (int i = 0; i < 2; ++i)
#pragma unroll
            for (int j = 0; j < 2; ++j) acc[i][j] = (f32x16)0.f;

        // single-buffered operands; 4 waves/SIMD provides the latency hiding
#pragma unroll 2
        for (int kt = 0; kt < 512; kt += 16) {
            bf16x8 a0 = *(const bf16x8*)(ap + kt);
            bf16x8 a1 = *(const bf16x8*)(ap + 32 * LDSR + kt);
            bf16x8 b0 = *(const bf16x8*)(bb0 + kt);
            bf16x8 b1 = *(const bf16x8*)(bb1 + kt);
            acc[0][0] = __builtin_amdgcn_mfma_f32_32x32x16_bf16(a0, b0, acc[0][0], 0, 0, 0);
            acc[0][1] = __builtin_amdgcn_mfma_f32_32x32x16_bf16(a0, b1, acc[0][1], 0, 0, 0);
            acc[1][0] = __builtin_amdgcn_mfma_f32_32x32x16_bf16(a1, b0, acc[1][0], 0, 0, 0);
            acc[1][1] = __builtin_amdgcn_mfma_f32_32x32x16_bf16(a1, b1, acc[1][1], 0, 0, 0);
        }

        // ---- epilogue (constants loaded here, not live during k-loop)
        float srcb[2], w1v[2], sp0v[2], sp1v[2], bk9v[2];
#pragma unroll
        for (int ni = 0; ni < 2; ++ni) {
            int fcol = f0 + ni * 32 + l31;
            srcb[ni] = H[(size_t)m * 3072 + 1024 + fcol] + sp_b0[fcol];
            w1v[ni]  = sp_W1[fcol];
            sp0v[ni] = spk_proj[fcol];
            sp1v[ni] = spk_proj[1024 + fcol];
            bk9v[ni] = bkt_proj[9 * 1024 + fcol];
        }
        // C/D 32x32 layout: col=lane&31, row=(reg&3)+8*(reg>>2)+4*(lane>>5)
#pragma unroll
        for (int mi = 0; mi < 2; ++mi) {
#pragma unroll
            for (int reg = 0; reg < 16; ++reg) {
                const int c = c0 + mi * 32 + 4 * k5 + (reg & 3) + 8 * (reg >> 2);
                int a = m - 1 - c; if (a < 0) a = 0;
                const int ss = meta_ss[c];
                const float* antp = H + (size_t)a * 3072 + 2048;
                float s = 0.f;
#pragma unroll
                for (int ni = 0; ni < 2; ++ni) {
                    const int fcol = f0 + ni * 32 + l31;
                    float bval = pass ? bk9v[ni] : bkt_proj[(size_t)meta_bk[c] * 1024 + fcol];
                    float pre = acc[mi][ni][reg] + srcb[ni] + antp[fcol] + (ss ? sp1v[ni] : sp0v[ni]) + bval;
                    s += fmaxf(pre, 0.f) * w1v[ni];
                }
                s += __shfl_xor(s, 1); s += __shfl_xor(s, 2); s += __shfl_xor(s, 4);
                s += __shfl_xor(s, 8); s += __shfl_xor(s, 16);
                if (l31 == 0) red[wave * 128 + c] = s;
            }
        }
    }
    __syncthreads();
    if (tid < 128) {
        float s = 0.f;
#pragma unroll
        for (int i = 0; i < 16; ++i) s += red[i * 128 + tid];
        slow[(size_t)m * 128 + tid] = s;
    }
}

// ---------------- softmax + per-mention loss
__device__ __forceinline__ float bsum2(float v, float* sm) {
#pragma unroll
    for (int o = 1; o < 64; o <<= 1) v += __shfl_xor(v, o);
    __syncthreads();
    if ((threadIdx.x & 63) == 0) sm[threadIdx.x >> 6] = v;
    __syncthreads();
    return sm[0] + sm[1];
}
__device__ __forceinline__ float bmax2(float v, float* sm) {
#pragma unroll
    for (int o = 1; o < 64; o <<= 1) v = fmaxf(v, __shfl_xor(v, o));
    __syncthreads();
    if ((threadIdx.x & 63) == 0) sm[threadIdx.x >> 6] = v;
    __syncthreads();
    return fmaxf(sm[0], sm[1]);
}

__global__ __launch_bounds__(128) void softmax_loss(
    const float* __restrict__ slow, const float* __restrict__ ms,
    const float* __restrict__ sp_b1, const int* __restrict__ cluster,
    float* __restrict__ out, float* __restrict__ loss_partial)
{
    const int m = blockIdx.x, c = threadIdx.x;
    __shared__ float sm[2];
    const int raw = m - 1 - c;
    const bool maskv = raw >= 0;
    const int a = maskv ? raw : 0;
    float score = slow[(size_t)m * 128 + c] + sp_b1[0] + ms[m] + ms[a];
    if (!maskv) score = -INFINITY;

    float mx = fmaxf(bmax2(score, sm), 0.f);
    float e = expf(score - mx);
    float e0 = expf(0.f - mx);
    float sum = bsum2(e, sm) + e0;
    float p = e / sum, p0 = e0 / sum;
    const float eps = 1e-6f;
    p  = fminf(fmaxf(p,  eps), 1.f - eps);
    p0 = fminf(fmaxf(p0, eps), 1.f - eps);
    float sum2 = bsum2(p, sm) + p0;
    p /= sum2; p0 /= sum2;
    out[(size_t)m * 129 + 1 + c] = p;
    if (c == 0) out[(size_t)m * 129] = p0;

    const int cid = cluster[m];
    const bool lbl = maskv && (cid > 0) && (cluster[a] == cid);
    float anyc = bsum2(lbl ? 1.f : 0.f, sm);
    float lsum = bsum2(lbl ? -logf(p) : 0.f, sm);
    if (c == 0) {
        if (anyc == 0.f) lsum += -logf(p0);
        loss_partial[m] = lsum;
    }
}

__global__ void loss_sum(const float* __restrict__ lp, float* __restrict__ out) {
    float v = 0.f;
    for (int i = threadIdx.x; i < 1024; i += 256) v += lp[i];
#pragma unroll
    for (int o = 1; o < 64; o <<= 1) v += __shfl_xor(v, o);
    __shared__ float sm[4];
    if ((threadIdx.x & 63) == 0) sm[threadIdx.x >> 6] = v;
    __syncthreads();
    if (threadIdx.x == 0) out[(size_t)1024 * 129] = sm[0] + sm[1] + sm[2] + sm[3];
}

extern "C" void kernel_launch(void* const* d_in, const int* in_sizes, int n_in,
                              void* d_out, int out_size, void* d_ws, size_t ws_size,
                              hipStream_t stream)
{
    const float* emb   = (const float*)d_in[0];
    const int*   clus  = (const int*)  d_in[1];
    const int*   spk   = (const int*)  d_in[2];
    const float* ms_W0 = (const float*)d_in[3];
    const float* ms_b0 = (const float*)d_in[4];
    const float* ms_W1 = (const float*)d_in[5];
    const float* ms_b1 = (const float*)d_in[6];
    const float* sp_W0 = (const float*)d_in[7];
    const float* sp_b0 = (const float*)d_in[8];
    const float* sp_W1 = (const float*)d_in[9];
    const float* sp_b1 = (const float*)d_in[10];
    const float* spke  = (const float*)d_in[11];
    const float* bkte  = (const float*)d_in[12];

    float* ws = (float*)d_ws;
    float* H        = ws;
    float* slow     = ws + 3145728;
    float* spk_proj = ws + 3276800;
    float* bkt_proj = ws + 3278848;
    float* msc      = ws + 3289088;
    float* lossp    = ws + 3290112;
    ushort* embb    = (ushort*)(ws + 3291136);
    ushort* Wall    = (ushort*)(ws + 3553280);
    ushort* Wt      = Wall + (size_t)3072 * 512;
    float* out = (float*)d_out;

    const int pair_lds = 128 * LDSR * 2 + 16 * 128 * 4 + 256 * 4;

    static bool attr_set = false;
    if (!attr_set) {
        hipFuncSetAttribute((const void*)pair_mfma,
                            hipFuncAttributeMaxDynamicSharedMemorySize,
                            pair_lds);
        attr_set = true;
    }

    hipLaunchKernelGGL(prep_emb, dim3(1024), dim3(256), 0, stream, emb, embb);
    hipLaunchKernelGGL(prep_wall, dim3(8, 64), dim3(256), 0, stream, ms_W0, sp_W0, Wall);
    hipLaunchKernelGGL(gemm_h_mfma, dim3(24, 8), dim3(256), 0, stream, embb, Wall, H);
    hipLaunchKernelGGL(small_proj, dim3(12), dim3(256), 0, stream, spke, bkte, sp_W0, spk_proj, bkt_proj);
    hipLaunchKernelGGL(mention_score, dim3(1024), dim3(256), 0, stream, H, ms_b0, ms_W1, ms_b1, msc);
    hipLaunchKernelGGL(pair_mfma, dim3(1024), dim3(1024), pair_lds, stream,
                       embb, Wt, H, spk_proj, bkt_proj, sp_b0, sp_W1, spk, slow);
    hipLaunchKernelGGL(softmax_loss, dim3(1024), dim3(128), 0, stream,
                       slow, msc, sp_b1, clus, out, lossp);
    hipLaunchKernelGGL(loss_sum, dim3(1), dim3(256), 0, stream, lossp, out);
}

// Round 7
// 374.448 us; speedup vs baseline: 2.3556x; 1.2970x over previous
//
#include <hip/hip_runtime.h>
#include <math.h>

// Problem constants (B=1)
#define MM 1024
#define DD 512
#define CC 128
#define LDSR 516   // A row stride in ushorts: 1032 B = 258 dw ≡ 2 (mod 32)
                   // -> lane start-bank 2l mod 32: 2-way = free (m136). 8B-aligned rows.

// ws layout (floats):
//  H[1024][3072]      @ 0        (0..1023 ms-hidden, 1024.. src_proj, 2048.. ant_proj)
//  slow[1024][128]    @ 3145728
//  spk_proj[2][1024]  @ 3276800
//  bkt_proj[10][1024] @ 3278848
//  ms[1024]           @ 3289088
//  lossp[1024]        @ 3290112
//  embb bf16[1024][512]  @ 3291136
//  Wall bf16[4096][512]  @ 3553280
//    rows [0,1024)=ms_W0^T, [1024,2048)=W_src^T, [2048,3072)=W_ant^T
//    region [3072,4096) reused as Wfrag: [tile t:32][kstep s:32][lane:64][8] bf16
//      element (f = t*32 + (lane&31), k = s*16 + (lane>>5)*8 + j) at ((t*32+s)*64+lane)*8+j

typedef __attribute__((ext_vector_type(8))) short bf16x8;
typedef __attribute__((ext_vector_type(4), aligned(8))) short bf16x4a;
typedef __attribute__((ext_vector_type(4))) float f32x4;
typedef __attribute__((ext_vector_type(16))) float f32x16;

__device__ __forceinline__ ushort bf16_rn(float x) {
    uint u = __float_as_uint(x);
    uint r = u + 0x7fffu + ((u >> 16) & 1u);
    return (ushort)(r >> 16);
}
__device__ __forceinline__ float bf16_to_f(ushort u) {
    return __uint_as_float(((uint)u) << 16);
}
__device__ __forceinline__ bf16x8 ld_lds16(const ushort* p) {   // two ds_read_b64
    bf16x4a lo = *(const bf16x4a*)p;
    bf16x4a hi = *(const bf16x4a*)(p + 4);
    return __builtin_shufflevector(lo, hi, 0, 1, 2, 3, 4, 5, 6, 7);
}

// ---------------- prep: emb fp32 -> bf16
__global__ __launch_bounds__(256) void prep_emb(const float* __restrict__ emb,
                                                ushort* __restrict__ embb)
{
    int i = blockIdx.x * 256 + threadIdx.x;
    float2 v = ((const float2*)emb)[i];
    ushort2 o;
    o.x = bf16_rn(v.x);
    o.y = bf16_rn(v.y);
    ((ushort2*)embb)[i] = o;
}

// ---------------- prep: transpose+convert W0 blocks 0..2 -> Wall[3072 n][512 k] bf16
__global__ __launch_bounds__(256) void prep_wall(const float* __restrict__ ms_W0,
                                                 const float* __restrict__ sp_W0,
                                                 ushort* __restrict__ Wall)
{
    __shared__ float t[64][65];
    const int k0 = blockIdx.x * 64;   // 8
    const int n0 = blockIdx.y * 64;   // 48
    const int g = n0 >> 10;
    const float* src = (g == 0) ? ms_W0 : (sp_W0 + (size_t)(g - 1) * 512 * 1024);
    const int col0 = n0 & 1023;
    const int tr = threadIdx.x >> 6, tc = threadIdx.x & 63;
#pragma unroll
    for (int i = 0; i < 16; ++i) {
        int k = tr + i * 4;
        t[k][tc] = src[(size_t)(k0 + k) * 1024 + col0 + tc];
    }
    __syncthreads();
    const int f = threadIdx.x >> 2;
    const int c4 = threadIdx.x & 3;
    ushort tmp[16];
#pragma unroll
    for (int j = 0; j < 16; ++j) tmp[j] = bf16_rn(t[c4 * 16 + j][f]);
    uint4* dst = (uint4*)(Wall + (size_t)(n0 + f) * 512 + k0 + c4 * 16);
    dst[0] = *(uint4*)&tmp[0];
    dst[1] = *(uint4*)&tmp[8];
}

// ---------------- prep: W_prod -> fragment-major Wfrag (wave load = contiguous 1 KB)
__global__ __launch_bounds__(64) void prep_wfrag(const float* __restrict__ sp_W0,
                                                 ushort* __restrict__ Wfrag)
{
    const int ts = blockIdx.x;            // t*32 + s, 0..1023
    const int l = threadIdx.x;            // 0..63
    const int tt = ts >> 5, s = ts & 31;
    const int f = tt * 32 + (l & 31);
    const int kb = s * 16 + (l >> 5) * 8;
    const float* W = sp_W0 + (size_t)1024 * 1024;   // W_prod [k=512][f=1024]
    ushort tmp[8];
#pragma unroll
    for (int j = 0; j < 8; ++j) tmp[j] = bf16_rn(W[(size_t)(kb + j) * 1024 + f]);
    uint4* dst = (uint4*)(Wfrag + ((size_t)ts * 64 + l) * 8);
    *dst = *(uint4*)&tmp[0];
}

// ---------------- H = emb @ [ms_W0 | W_src | W_ant] via MFMA (1024x512x3072)
__global__ __launch_bounds__(256) void gemm_h_mfma(
    const ushort* __restrict__ embb, const ushort* __restrict__ Wall,
    float* __restrict__ H)
{
    const int n0 = blockIdx.x * 128;  // 24
    const int m0 = blockIdx.y * 128;  // 8
    const int lane = threadIdx.x & 63, wave = threadIdx.x >> 6;
    const int wx = wave & 1, wy = wave >> 1;
    const int l15 = lane & 15, lq = lane >> 4;

    const ushort* arow[4];
#pragma unroll
    for (int mi = 0; mi < 4; ++mi)
        arow[mi] = embb + (size_t)(m0 + wy * 64 + mi * 16 + l15) * 512;
    const ushort* brow[4];
#pragma unroll
    for (int ni = 0; ni < 4; ++ni)
        brow[ni] = Wall + (size_t)(n0 + wx * 64 + ni * 16 + l15) * 512;

    f32x4 acc[4][4];
#pragma unroll
    for (int i = 0; i < 4; ++i)
#pragma unroll
        for (int j = 0; j < 4; ++j) acc[i][j] = (f32x4)0.f;

    for (int kt = 0; kt < 512; kt += 32) {
        const int ko = kt + lq * 8;
        bf16x8 av[4], bv[4];
#pragma unroll
        for (int mi = 0; mi < 4; ++mi) av[mi] = *(const bf16x8*)(arow[mi] + ko);
#pragma unroll
        for (int ni = 0; ni < 4; ++ni) bv[ni] = *(const bf16x8*)(brow[ni] + ko);
#pragma unroll
        for (int mi = 0; mi < 4; ++mi)
#pragma unroll
            for (int ni = 0; ni < 4; ++ni)
                acc[mi][ni] = __builtin_amdgcn_mfma_f32_16x16x32_bf16(av[mi], bv[ni], acc[mi][ni], 0, 0, 0);
    }
#pragma unroll
    for (int mi = 0; mi < 4; ++mi)
#pragma unroll
        for (int r = 0; r < 4; ++r) {
            int mrow = m0 + wy * 64 + mi * 16 + lq * 4 + r;
#pragma unroll
            for (int ni = 0; ni < 4; ++ni)
                H[(size_t)mrow * 3072 + n0 + wx * 64 + ni * 16 + l15] = acc[mi][ni][r];
        }
}

// ---------------- small projections
__global__ void small_proj(const float* __restrict__ speaker_emb,
                           const float* __restrict__ bucket_emb,
                           const float* __restrict__ sp_W0,
                           float* __restrict__ spk_proj, float* __restrict__ bkt_proj)
{
    int r = blockIdx.x; // 0..11
    const float* e; const float* W; float* out;
    if (r < 2) { e = speaker_emb + r * 20; W = sp_W0 + (size_t)1536 * 1024; out = spk_proj + r * 1024; }
    else       { e = bucket_emb + (r - 2) * 20; W = sp_W0 + (size_t)1556 * 1024; out = bkt_proj + (r - 2) * 1024; }
    float ek[20];
#pragma unroll
    for (int k = 0; k < 20; ++k) ek[k] = e[k];
    for (int f = threadIdx.x; f < 1024; f += blockDim.x) {
        float s = 0.f;
#pragma unroll
        for (int k = 0; k < 20; ++k) s = fmaf(ek[k], W[(size_t)k * 1024 + f], s);
        out[f] = s;
    }
}

// ---------------- mention scores
__global__ __launch_bounds__(256) void mention_score(
    const float* __restrict__ H, const float* __restrict__ ms_b0,
    const float* __restrict__ ms_W1, const float* __restrict__ ms_b1,
    float* __restrict__ ms)
{
    int m = blockIdx.x;
    float v = 0.f;
    for (int f = threadIdx.x; f < 1024; f += 256) {
        float h = H[(size_t)m * 3072 + f] + ms_b0[f];
        v += fmaxf(h, 0.f) * ms_W1[f];
    }
#pragma unroll
    for (int o = 1; o < 64; o <<= 1) v += __shfl_xor(v, o);
    __shared__ float sm[4];
    if ((threadIdx.x & 63) == 0) sm[threadIdx.x >> 6] = v;
    __syncthreads();
    if (threadIdx.x == 0) ms[m] = sm[0] + sm[1] + sm[2] + sm[3] + ms_b1[0];
}

// ---------------- pair scorer: 16 waves (4/SIMD); 32x32x16 MFMA; A in LDS (stride 516),
// B fragment-major (wave load = contiguous 1 KB)
__global__ __launch_bounds__(1024, 4) void pair_mfma(
    const ushort* __restrict__ embb, const ushort* __restrict__ Wfrag,
    const float* __restrict__ H, const float* __restrict__ spk_proj,
    const float* __restrict__ bkt_proj, const float* __restrict__ sp_b0,
    const float* __restrict__ sp_W1, const int* __restrict__ speaker,
    float* __restrict__ slow)
{
    extern __shared__ ushort Alds[];                  // 128*LDSR ushorts
    float* red = (float*)(Alds + 128 * LDSR);         // 16*128 floats
    int* meta_ss = (int*)(red + 16 * 128);            // 128 ints
    int* meta_bk = meta_ss + 128;                     // 128 ints
    const int m = blockIdx.x;
    const int tid = threadIdx.x;
    const int spk_m = speaker[m];

    // ---- build A[c][k] = bf16(em[k]*ea[k]) in LDS + per-c metadata
    {
        const int c = tid >> 3;                       // 0..127
        const int kh = (tid & 7) * 64;
        int a = m - 1 - c; if (a < 0) a = 0;
        const ushort* ea = embb + (size_t)a * 512 + kh;
        const ushort* em = embb + (size_t)m * 512 + kh;
        ushort* dst = Alds + c * LDSR + kh;
#pragma unroll
        for (int j = 0; j < 64; j += 8) {
            bf16x8 va = *(const bf16x8*)(ea + j);
            bf16x8 vm = *(const bf16x8*)(em + j);
            uint pr[4];
#pragma unroll
            for (int p = 0; p < 4; ++p) {
                float q0 = bf16_to_f((ushort)va[2 * p])     * bf16_to_f((ushort)vm[2 * p]);
                float q1 = bf16_to_f((ushort)va[2 * p + 1]) * bf16_to_f((ushort)vm[2 * p + 1]);
                pr[p] = __builtin_amdgcn_perm(__float_as_uint(q1), __float_as_uint(q0), 0x07060302u);
            }
            *(uint2*)(dst + j)     = *(uint2*)&pr[0];   // 8B stores (rows are 8B-aligned)
            *(uint2*)(dst + j + 4) = *(uint2*)&pr[2];
        }
        if ((tid & 7) == 0) {
            meta_ss[c] = (speaker[a] == spk_m) ? 1 : 0;
            int off = c + 1;
            int bk;
            if (off <= 4) bk = off;
            else { bk = 31 - __clz(off) + 3; if (bk > 9) bk = 9; }
            meta_bk[c] = bk;
        }
    }
    __syncthreads();

    const int lane = tid & 63;
    const int wave = __builtin_amdgcn_readfirstlane(tid >> 6);   // 0..15, wave-uniform
    const int l31 = lane & 31, k5 = lane >> 5;
    const int f0 = wave * 64;

    // B: fragment-major; per k-step s the wave reads contiguous 1 KB per tile
    const ushort* bb = Wfrag + (size_t)(wave * 2) * 16384 + (size_t)lane * 8;
    const ushort* ab = Alds + l31 * LDSR + k5 * 8;

    for (int pass = 0; pass < 2; ++pass) {
        const int c0 = pass * 64;
        const ushort* ap = ab + c0 * LDSR;
        f32x16 acc[2][2];
#pragma unroll
        for (int i = 0; i < 2; ++i)
#pragma unroll
            for (int j = 0; j < 2; ++j) acc[i][j] = (f32x16)0.f;

#pragma unroll 2
        for (int s = 0; s < 32; ++s) {
            bf16x8 b0 = *(const bf16x8*)(bb + s * 512);
            bf16x8 b1 = *(const bf16x8*)(bb + 16384 + s * 512);
            bf16x8 a0 = ld_lds16(ap + s * 16);
            bf16x8 a1 = ld_lds16(ap + 32 * LDSR + s * 16);
            acc[0][0] = __builtin_amdgcn_mfma_f32_32x32x16_bf16(a0, b0, acc[0][0], 0, 0, 0);
            acc[0][1] = __builtin_amdgcn_mfma_f32_32x32x16_bf16(a0, b1, acc[0][1], 0, 0, 0);
            acc[1][0] = __builtin_amdgcn_mfma_f32_32x32x16_bf16(a1, b0, acc[1][0], 0, 0, 0);
            acc[1][1] = __builtin_amdgcn_mfma_f32_32x32x16_bf16(a1, b1, acc[1][1], 0, 0, 0);
        }

        // ---- epilogue (constants loaded here, not live during k-loop)
        float srcb[2], w1v[2], sp0v[2], sp1v[2], bk9v[2];
#pragma unroll
        for (int ni = 0; ni < 2; ++ni) {
            int fcol = f0 + ni * 32 + l31;
            srcb[ni] = H[(size_t)m * 3072 + 1024 + fcol] + sp_b0[fcol];
            w1v[ni]  = sp_W1[fcol];
            sp0v[ni] = spk_proj[fcol];
            sp1v[ni] = spk_proj[1024 + fcol];
            bk9v[ni] = bkt_proj[9 * 1024 + fcol];
        }
        // C/D 32x32 layout: col=lane&31, row=(reg&3)+8*(reg>>2)+4*(lane>>5)
#pragma unroll
        for (int mi = 0; mi < 2; ++mi) {
#pragma unroll
            for (int reg = 0; reg < 16; ++reg) {
                const int c = c0 + mi * 32 + 4 * k5 + (reg & 3) + 8 * (reg >> 2);
                int a = m - 1 - c; if (a < 0) a = 0;
                const int ss = meta_ss[c];
                const float* antp = H + (size_t)a * 3072 + 2048;
                float s = 0.f;
#pragma unroll
                for (int ni = 0; ni < 2; ++ni) {
                    const int fcol = f0 + ni * 32 + l31;
                    float bval = pass ? bk9v[ni] : bkt_proj[(size_t)meta_bk[c] * 1024 + fcol];
                    float pre = acc[mi][ni][reg] + srcb[ni] + antp[fcol] + (ss ? sp1v[ni] : sp0v[ni]) + bval;
                    s += fmaxf(pre, 0.f) * w1v[ni];
                }
                s += __shfl_xor(s, 1); s += __shfl_xor(s, 2); s += __shfl_xor(s, 4);
                s += __shfl_xor(s, 8); s += __shfl_xor(s, 16);
                if (l31 == 0) red[wave * 128 + c] = s;
            }
        }
    }
    __syncthreads();
    if (tid < 128) {
        float s = 0.f;
#pragma unroll
        for (int i = 0; i < 16; ++i) s += red[i * 128 + tid];
        slow[(size_t)m * 128 + tid] = s;
    }
}

// ---------------- softmax + per-mention loss
__device__ __forceinline__ float bsum2(float v, float* sm) {
#pragma unroll
    for (int o = 1; o < 64; o <<= 1) v += __shfl_xor(v, o);
    __syncthreads();
    if ((threadIdx.x & 63) == 0) sm[threadIdx.x >> 6] = v;
    __syncthreads();
    return sm[0] + sm[1];
}
__device__ __forceinline__ float bmax2(float v, float* sm) {
#pragma unroll
    for (int o = 1; o < 64; o <<= 1) v = fmaxf(v, __shfl_xor(v, o));
    __syncthreads();
    if ((threadIdx.x & 63) == 0) sm[threadIdx.x >> 6] = v;
    __syncthreads();
    return fmaxf(sm[0], sm[1]);
}

__global__ __launch_bounds__(128) void softmax_loss(
    const float* __restrict__ slow, const float* __restrict__ ms,
    const float* __restrict__ sp_b1, const int* __restrict__ cluster,
    float* __restrict__ out, float* __restrict__ loss_partial)
{
    const int m = blockIdx.x, c = threadIdx.x;
    __shared__ float sm[2];
    const int raw = m - 1 - c;
    const bool maskv = raw >= 0;
    const int a = maskv ? raw : 0;
    float score = slow[(size_t)m * 128 + c] + sp_b1[0] + ms[m] + ms[a];
    if (!maskv) score = -INFINITY;

    float mx = fmaxf(bmax2(score, sm), 0.f);
    float e = expf(score - mx);
    float e0 = expf(0.f - mx);
    float sum = bsum2(e, sm) + e0;
    float p = e / sum, p0 = e0 / sum;
    const float eps = 1e-6f;
    p  = fminf(fmaxf(p,  eps), 1.f - eps);
    p0 = fminf(fmaxf(p0, eps), 1.f - eps);
    float sum2 = bsum2(p, sm) + p0;
    p /= sum2; p0 /= sum2;
    out[(size_t)m * 129 + 1 + c] = p;
    if (c == 0) out[(size_t)m * 129] = p0;

    const int cid = cluster[m];
    const bool lbl = maskv && (cid > 0) && (cluster[a] == cid);
    float anyc = bsum2(lbl ? 1.f : 0.f, sm);
    float lsum = bsum2(lbl ? -logf(p) : 0.f, sm);
    if (c == 0) {
        if (anyc == 0.f) lsum += -logf(p0);
        loss_partial[m] = lsum;
    }
}

__global__ void loss_sum(const float* __restrict__ lp, float* __restrict__ out) {
    float v = 0.f;
    for (int i = threadIdx.x; i < 1024; i += 256) v += lp[i];
#pragma unroll
    for (int o = 1; o < 64; o <<= 1) v += __shfl_xor(v, o);
    __shared__ float sm[4];
    if ((threadIdx.x & 63) == 0) sm[threadIdx.x >> 6] = v;
    __syncthreads();
    if (threadIdx.x == 0) out[(size_t)1024 * 129] = sm[0] + sm[1] + sm[2] + sm[3];
}

extern "C" void kernel_launch(void* const* d_in, const int* in_sizes, int n_in,
                              void* d_out, int out_size, void* d_ws, size_t ws_size,
                              hipStream_t stream)
{
    const float* emb   = (const float*)d_in[0];
    const int*   clus  = (const int*)  d_in[1];
    const int*   spk   = (const int*)  d_in[2];
    const float* ms_W0 = (const float*)d_in[3];
    const float* ms_b0 = (const float*)d_in[4];
    const float* ms_W1 = (const float*)d_in[5];
    const float* ms_b1 = (const float*)d_in[6];
    const float* sp_W0 = (const float*)d_in[7];
    const float* sp_b0 = (const float*)d_in[8];
    const float* sp_W1 = (const float*)d_in[9];
    const float* sp_b1 = (const float*)d_in[10];
    const float* spke  = (const float*)d_in[11];
    const float* bkte  = (const float*)d_in[12];

    float* ws = (float*)d_ws;
    float* H        = ws;
    float* slow     = ws + 3145728;
    float* spk_proj = ws + 3276800;
    float* bkt_proj = ws + 3278848;
    float* msc      = ws + 3289088;
    float* lossp    = ws + 3290112;
    ushort* embb    = (ushort*)(ws + 3291136);
    ushort* Wall    = (ushort*)(ws + 3553280);
    ushort* Wfrag   = Wall + (size_t)3072 * 512;   // reuse W_prod region, frag-major
    float* out = (float*)d_out;

    const int pair_lds = 128 * LDSR * 2 + 16 * 128 * 4 + 256 * 4;

    static bool attr_set = false;
    if (!attr_set) {
        hipFuncSetAttribute((const void*)pair_mfma,
                            hipFuncAttributeMaxDynamicSharedMemorySize,
                            pair_lds);
        attr_set = true;
    }

    hipLaunchKernelGGL(prep_emb, dim3(1024), dim3(256), 0, stream, emb, embb);
    hipLaunchKernelGGL(prep_wall, dim3(8, 48), dim3(256), 0, stream, ms_W0, sp_W0, Wall);
    hipLaunchKernelGGL(prep_wfrag, dim3(1024), dim3(64), 0, stream, sp_W0, Wfrag);
    hipLaunchKernelGGL(gemm_h_mfma, dim3(24, 8), dim3(256), 0, stream, embb, Wall, H);
    hipLaunchKernelGGL(small_proj, dim3(12), dim3(256), 0, stream, spke, bkte, sp_W0, spk_proj, bkt_proj);
    hipLaunchKernelGGL(mention_score, dim3(1024), dim3(256), 0, stream, H, ms_b0, ms_W1, ms_b1, msc);
    hipLaunchKernelGGL(pair_mfma, dim3(1024), dim3(1024), pair_lds, stream,
                       embb, Wfrag, H, spk_proj, bkt_proj, sp_b0, sp_W1, spk, slow);
    hipLaunchKernelGGL(softmax_loss, dim3(1024), dim3(128), 0, stream,
                       slow, msc, sp_b1, clus, out, lossp);
    hipLaunchKernelGGL(loss_sum, dim3(1), dim3(256), 0, stream, lossp, out);
}